// Round 6
// baseline (447.197 us; speedup 1.0000x reference)
//
#include <hip/hip_runtime.h>
#include <math.h>

#define CIN    128
#define HID    128
#define HDIM   64
#define WDIM   64
#define HW     4096
#define NTOT   512
#define LDSROW 136      // shorts per A-row: 128 + 8 pad (272 B)
#define NBATCH 16
#define WXSZ   (4 * 8 * 64 * 8)    // 16384 shorts per he-slice (x-part frag)
#define WHSZ   (4 * 12 * 64 * 8)   // 24576 shorts per he-slice (h-part frag)
#define HTWORDS (2 * NBATCH * WDIM * HID)  // 262144 tagged u32

typedef short short8 __attribute__((ext_vector_type(8)));
typedef float f32x4  __attribute__((ext_vector_type(4)));
typedef unsigned int u32x4 __attribute__((ext_vector_type(4)));

#define ALOAD(p)     __hip_atomic_load((p), __ATOMIC_RELAXED, __HIP_MEMORY_SCOPE_AGENT)
#define ASTORE(p, v) __hip_atomic_store((p), (v), __ATOMIC_RELAXED, __HIP_MEMORY_SCOPE_AGENT)

// z fragment layout: float index (((((b*8+he)*64+r)*4+wv)*4+g)*64+lane)*4 + e
#define Z_IDX(b_, he_, r_, wv_, g_, lane_) \
    ((((((((size_t)(b_) * 8 + (he_)) * 64 + (r_)) * 4 + (wv_)) * 4 + (g_)) * 64) + (lane_)) * 4)

__device__ __forceinline__ unsigned short f2bf(float f) {
    union { float f; unsigned int u; } v; v.f = f;
    unsigned int r = v.u + 0x7fffu + ((v.u >> 16) & 1u);   // RNE
    return (unsigned short)(r >> 16);
}
__device__ __forceinline__ float sigm(float x)  { return 1.0f / (1.0f + __expf(-x)); }
__device__ __forceinline__ float tanhft(float x){ return 2.0f / (1.0f + __expf(-2.0f * x)) - 1.0f; }

// ---------------------------------------------------------------------------
// Pack: Wx (x-part) and Wh (h-part) in FRAGMENT order, bias fold, zero tags.
//   Wx idx = (((he*4+g)*8 + ks)*64 + lane)*8 + j ; k = ks*32+(lane>>4)*8+j (0..255)
//   Wh idx = (((he*4+g)*12+ ks)*64 + lane)*8 + j ; k = ks*32+(lane>>4)*8+j (0..383)
//   n = g*128 + he*16 + (lane&15)
// ---------------------------------------------------------------------------
__global__ void pack_kernel(const float* __restrict__ W_is,
                            const float* __restrict__ b_is,
                            const float* __restrict__ W_ss,
                            const float* __restrict__ b_ss,
                            unsigned short* __restrict__ Wx,
                            unsigned short* __restrict__ Wh,
                            float* __restrict__ bias_p,
                            unsigned int* __restrict__ ht) {
    int idx = blockIdx.x * blockDim.x + threadIdx.x;
    if (idx < 131072) {                 // 8 he * WXSZ
        int j = idx & 7, lane = (idx >> 3) & 63, rest = idx >> 9;
        int ks = rest & 7, gg = rest >> 3, g = gg & 3, he = gg >> 2;
        int n = g * 128 + he * 16 + (lane & 15);
        int k = ks * 32 + ((lane >> 4) * 8) + j;
        Wx[idx] = f2bf(W_is[((size_t)n * CIN + (k & 127)) * 3 + (k >> 7)]);
    }
    if (idx < 196608) {                 // 8 he * WHSZ
        int j = idx & 7, lane = (idx >> 3) & 63, rest = idx >> 9;   // rest<384
        int ks = rest % 12, gg = rest / 12, g = gg & 3, he = gg >> 2;
        int n = g * 128 + he * 16 + (lane & 15);
        int k = ks * 32 + ((lane >> 4) * 8) + j;
        Wh[idx] = f2bf(W_ss[((size_t)n * HID + (k & 127)) * 3 + (k >> 7)]);
    }
    if (idx < NTOT) bias_p[idx] = b_is[idx] + b_ss[idx];
    if (idx < HTWORDS) ht[idx] = 0u;    // tags reset every launch (replay-safe)
}

#define STAGE_X(ROW, BUF)                                                      \
    {                                                                          \
        const float* xrow = x + (size_t)b * (CIN * HW) + (size_t)(ROW) * WDIM; \
        _Pragma("unroll")                                                      \
        for (int p = 0; p < 16; ++p) {                                         \
            int flat = p * 256 + tid;                                          \
            int w  = flat & 63;                                                \
            int cp = flat >> 6;                                                \
            float v0 = xrow[(2 * cp    ) * HW + w];                            \
            float v1 = xrow[(2 * cp + 1) * HW + w];                            \
            ((unsigned*)(BUF))[(w + 1) * 68 + cp] =                            \
                (unsigned)f2bf(v0) | ((unsigned)f2bf(v1) << 16);               \
        }                                                                      \
    }

#define GEMM_X(BUF)                                                            \
    {                                                                          \
        _Pragma("unroll")                                                      \
        for (int ks = 0; ks < 8; ++ks) {                                       \
            const int t = ks >> 2, c0 = (ks & 3) * 32;                         \
            short8 a = *(const short8*)&(BUF)[(wv * 16 + t) * LDSROW + c0 + a_off]; \
            _Pragma("unroll")                                                  \
            for (int g = 0; g < 4; ++g) {                                      \
                short8 bq = *(const short8*)&lds_bx[((g * 8 + ks) * 64 + lane) * 8]; \
                acc[g] = __builtin_amdgcn_mfma_f32_16x16x32_bf16(a, bq, acc[g], 0, 0, 0); \
            }                                                                  \
        }                                                                      \
    }

#define GEMM_H(LDSH)                                                           \
    {                                                                          \
        _Pragma("unroll")                                                      \
        for (int ks = 0; ks < 12; ++ks) {                                      \
            const int t = ks >> 2, c0 = (ks & 3) * 32;                         \
            short8 a = *(const short8*)&(LDSH)[(wv * 16 + t) * LDSROW + c0 + a_off]; \
            _Pragma("unroll")                                                  \
            for (int g = 0; g < 4; ++g) {                                      \
                short8 bq = *(const short8*)&lds_bh[((g * 12 + ks) * 64 + lane) * 8]; \
                acc[g] = __builtin_amdgcn_mfma_f32_16x16x32_bf16(a, bq, acc[g], 0, 0, 0); \
            }                                                                  \
        }                                                                      \
    }

// Tagged poll+load: per lane 18 rows x 2 channels (ch = 2*lane, 2*lane+1).
// Word = (bf16 << 16) | tag. Retry until ALL tags == WANT; the passing
// iteration already holds the data (1 L3 round-trip handshake). Halo rows
// synthesize (WANT) -> bf16 0, tag pass. Then transpose into LDS [row][ch].
#define POLL_H(PAR, WANT, LDSH)                                                \
    {                                                                          \
        const unsigned* hs = ht + ((size_t)(PAR) * NBATCH + b) * (WDIM * HID); \
        unsigned a_[18], b_[18];                                               \
        const int base = wv * 16 - 1;                                          \
        for (;;) {                                                             \
            unsigned diff = 0;                                                 \
            _Pragma("unroll")                                                  \
            for (int i = 0; i < 18; ++i) {                                     \
                int rr = base + i;                                             \
                unsigned va, vb;                                               \
                if ((unsigned)rr < 64u) {                                      \
                    const unsigned* p = hs + rr * 128 + 2 * lane;              \
                    va = ALOAD(p); vb = ALOAD(p + 1);                          \
                } else { va = vb = (unsigned)(WANT); }                         \
                a_[i] = va; b_[i] = vb;                                        \
                diff |= ((va ^ (unsigned)(WANT)) | (vb ^ (unsigned)(WANT))) & 0xffffu; \
            }                                                                  \
            if (__ballot(diff != 0u) == 0ull) break;                           \
        }                                                                      \
        _Pragma("unroll")                                                      \
        for (int i = 0; i < 18; ++i) {                                         \
            int rr = base + i;                                                 \
            ((unsigned*)(LDSH))[(rr + 1) * 68 + lane] =                        \
                (a_[i] >> 16) | (b_[i] & 0xffff0000u);                         \
        }                                                                      \
    }

// ---------------------------------------------------------------------------
// xgemm: z_x for ALL rows at high occupancy. grid 1024 = (b, he, rgroup of 8).
// Stores raw f32 MFMA sums in fragment layout (consumer adds bias).
// ---------------------------------------------------------------------------
__global__ __launch_bounds__(256) void xgemm_kernel(
        const float* __restrict__ x,
        const unsigned short* __restrict__ Wx,
        float* __restrict__ z) {
    __shared__ __align__(16) unsigned short lds_bx[WXSZ];          // 32 KiB
    __shared__ __align__(16) unsigned short ldsx[2][66 * LDSROW];  // 2 x 17.5 KiB

    const int tid  = threadIdx.x;
    const int b    = blockIdx.x & 15;
    const int he   = (blockIdx.x >> 4) & 7;
    const int rg   = blockIdx.x >> 7;          // 0..7
    const int wv   = tid >> 6;
    const int lane = tid & 63;
    const int quad = lane >> 4;
    const int l15  = lane & 15;
    const int a_off = l15 * LDSROW + quad * 8;

    {
        const u32x4* src = (const u32x4*)(Wx + (size_t)he * WXSZ);
        u32x4* dst = (u32x4*)lds_bx;
#pragma unroll
        for (int p = 0; p < 8; ++p) dst[p * 256 + tid] = src[p * 256 + tid];
    }
    if (tid < 68) { ((unsigned*)ldsx[0])[tid] = 0; ((unsigned*)ldsx[1])[tid] = 0; }

    for (int rr = 0; rr < 8; ++rr) {
        const int r = rg * 8 + rr;
        STAGE_X(r, ldsx[rr & 1]);
        __syncthreads();
        f32x4 acc[4];
#pragma unroll
        for (int g = 0; g < 4; ++g) acc[g] = (f32x4){0.f, 0.f, 0.f, 0.f};
        GEMM_X(ldsx[rr & 1]);
#pragma unroll
        for (int g = 0; g < 4; ++g)
            *(f32x4*)(z + Z_IDX(b, he, r, wv, g, lane)) = acc[g];
    }
}

// ---------------------------------------------------------------------------
// Persistent LSTM kernel: grid 128 = (b, he), 256 thr, 1 blk/CU, all resident.
// USE_Z: no x-path in the loop, no __syncthreads in the loop, waves fully
// autonomous. Per row: prefetch z frag -> tagged poll (data IS the flag) ->
// LDS transpose -> GEMM_H -> epilogue -> 4 tagged h stores (self-publishing,
// no drain). Parity ping-pong on ht; c-state in registers.
// ---------------------------------------------------------------------------
template <bool USE_Z>
__global__ __launch_bounds__(256, 1) void lstm_kernel(
        const float* __restrict__ x,
        const unsigned short* __restrict__ Wx,
        const unsigned short* __restrict__ Wh,
        const float* __restrict__ bias_p,
        const float* __restrict__ z,
        unsigned int* ht,
        float* __restrict__ out) {
    __shared__ __align__(16) unsigned short lds_bh[WHSZ];                       // 48 KiB
    __shared__ __align__(16) unsigned short lds_bx[USE_Z ? 16 : WXSZ];          // fb: 32 KiB
    __shared__ __align__(16) unsigned short ldsx[2][USE_Z ? 16 : 66 * LDSROW];  // fb: 35 KiB
    __shared__ __align__(16) unsigned short ldsh[2][66 * LDSROW];               // 35 KiB

    const int tid  = threadIdx.x;
    const int b    = blockIdx.x & 15;      // partners share bid%8 -> same XCD
    const int he   = blockIdx.x >> 4;
    const int wv   = tid >> 6;
    const int lane = tid & 63;
    const int quad = lane >> 4;
    const int l15  = lane & 15;
    const int a_off = l15 * LDSROW + quad * 8;

    {
        const u32x4* src = (const u32x4*)(Wh + (size_t)he * WHSZ);
        u32x4* dst = (u32x4*)lds_bh;
#pragma unroll
        for (int p = 0; p < 12; ++p) dst[p * 256 + tid] = src[p * 256 + tid];
    }
    if constexpr (!USE_Z) {
        const u32x4* src = (const u32x4*)(Wx + (size_t)he * WXSZ);
        u32x4* dst = (u32x4*)lds_bx;
#pragma unroll
        for (int p = 0; p < 8; ++p) dst[p * 256 + tid] = src[p * 256 + tid];
        if (tid < 68) { ((unsigned*)ldsx[0])[tid] = 0; ((unsigned*)ldsx[1])[tid] = 0; }
        STAGE_X(0, ldsx[0]);
    }
    __syncthreads();

    const int hch = he * 16 + l15;
    const float bi  = bias_p[      hch];
    const float bf_ = bias_p[128 + hch];
    const float bo  = bias_p[256 + hch];
    const float bg  = bias_p[384 + hch];

    f32x4 acc[4];
#pragma unroll
    for (int g = 0; g < 4; ++g) acc[g] = (f32x4){0.f, 0.f, 0.f, 0.f};
    f32x4 creg = (f32x4){0.f, 0.f, 0.f, 0.f};
    f32x4 zx[4];

    if constexpr (!USE_Z) GEMM_X(ldsx[0]);     // x-part of row 0

    for (int r = 0; r < HDIM; ++r) {
        if constexpr (USE_Z) {
            // prefetch z frag for row r (independent of h -> before the poll)
            const float* zb = z + Z_IDX(b, he, r, wv, 0, lane);
#pragma unroll
            for (int g = 0; g < 4; ++g) zx[g] = *(const f32x4*)(zb + g * 256);
#pragma unroll
            for (int g = 0; g < 4; ++g) acc[g] = (f32x4){0.f, 0.f, 0.f, 0.f};
        } else {
            if (r < HDIM - 1) STAGE_X(r + 1, ldsx[(r + 1) & 1]);
        }

        if (r > 0) {
            const int par = (r - 1) & 1;
            POLL_H(par, r, ldsh[par]);
            GEMM_H(ldsh[par]);
        }

        // ---- LSTM epilogue: gates lane-local; c stays in registers ----
        {
            const int w0 = wv * 16 + quad * 4;
            f32x4 hv;
#pragma unroll
            for (int e = 0; e < 4; ++e) {
                float zi, zf, zo, zg;
                if constexpr (USE_Z) {
                    zi = zx[0][e] + acc[0][e] + bi;
                    zf = zx[1][e] + acc[1][e] + bf_;
                    zo = zx[2][e] + acc[2][e] + bo;
                    zg = zx[3][e] + acc[3][e] + bg;
                } else {
                    zi = acc[0][e] + bi;
                    zf = acc[1][e] + bf_;
                    zo = acc[2][e] + bo;
                    zg = acc[3][e] + bg;
                }
                float ig = sigm(zi), fg = sigm(zf), og = sigm(zo);
                float gg = tanhft(zg);
                float cn = fg * creg[e] + ig * gg;
                creg[e] = cn;
                hv[e]   = og * tanhft(cn);
            }
            // tagged, self-publishing h stores (no drain, no flags)
            unsigned* hb = ht + ((size_t)(r & 1) * NBATCH + b) * (WDIM * HID);
#pragma unroll
            for (int e = 0; e < 4; ++e)
                ASTORE(&hb[(w0 + e) * 128 + hch],
                       ((unsigned)f2bf(hv[e]) << 16) | (unsigned)(r + 1));
            *(f32x4*)&out[(((size_t)b * HID + hch) * HDIM + r) * WDIM + w0] = hv;
        }

        if constexpr (!USE_Z) {
            if (r < HDIM - 1) {
                __syncthreads();           // x-stage fence only (fallback path)
#pragma unroll
                for (int g = 0; g < 4; ++g) acc[g] = (f32x4){0.f, 0.f, 0.f, 0.f};
                GEMM_X(ldsx[(r + 1) & 1]);
            }
        }
    }
}

extern "C" void kernel_launch(void* const* d_in, const int* in_sizes, int n_in,
                              void* d_out, int out_size, void* d_ws, size_t ws_size,
                              hipStream_t stream) {
    const float* x    = (const float*)d_in[0];
    const float* W_is = (const float*)d_in[1];
    const float* b_is = (const float*)d_in[2];
    const float* W_ss = (const float*)d_in[3];
    const float* b_ss = (const float*)d_in[4];
    float* out = (float*)d_out;

    const size_t Z_BYTES  = (size_t)33554432 * 4;   // 134217728
    const size_t HT_BYTES = (size_t)HTWORDS * 4;    // 1048576
    const size_t WX_BYTES = 8 * WXSZ * 2;           // 262144
    const size_t WH_BYTES = 8 * WHSZ * 2;           // 393216
    const size_t need_z   = Z_BYTES + HT_BYTES + WX_BYTES + WH_BYTES + 2048;

    if (ws_size >= need_z) {
        float*          zbuf   = (float*)d_ws;
        unsigned int*   ht     = (unsigned int*)((char*)d_ws + Z_BYTES);
        unsigned short* Wx     = (unsigned short*)((char*)d_ws + Z_BYTES + HT_BYTES);
        unsigned short* Wh     = (unsigned short*)((char*)d_ws + Z_BYTES + HT_BYTES + WX_BYTES);
        float*          bias_p = (float*)((char*)d_ws + Z_BYTES + HT_BYTES + WX_BYTES + WH_BYTES);

        pack_kernel<<<1024, 256, 0, stream>>>(W_is, b_is, W_ss, b_ss, Wx, Wh, bias_p, ht);
        xgemm_kernel<<<1024, 256, 0, stream>>>(x, Wx, zbuf);
        lstm_kernel<true><<<128, 256, 0, stream>>>(x, Wx, Wh, bias_p, zbuf, ht, out);
    } else {
        unsigned int*   ht     = (unsigned int*)d_ws;
        unsigned short* Wx     = (unsigned short*)((char*)d_ws + HT_BYTES);
        unsigned short* Wh     = (unsigned short*)((char*)d_ws + HT_BYTES + WX_BYTES);
        float*          bias_p = (float*)((char*)d_ws + HT_BYTES + WX_BYTES + WH_BYTES);

        pack_kernel<<<1024, 256, 0, stream>>>(W_is, b_is, W_ss, b_ss, Wx, Wh, bias_p, ht);
        lstm_kernel<false><<<128, 256, 0, stream>>>(x, Wx, Wh, bias_p, (const float*)d_ws, ht, out);
    }
}

// Round 7
// 398.418 us; speedup vs baseline: 1.1224x; 1.1224x over previous
//
#include <hip/hip_runtime.h>
#include <math.h>

#define CIN    128
#define HID    128
#define HDIM   64
#define WDIM   64
#define HW     4096
#define NBATCH 16
#define LROW   136                  // shorts per LDS row (272 B = 16*17, b128-aligned)
#define WXSZ   (4 * 8 * 64 * 8)    // 16384 shorts per he-slice (x-part frag)
#define WHSZ   (4 * 12 * 64 * 8)   // 24576 shorts per he-slice (h-part frag, ch-grouped)
#define HTWORDS (2 * NBATCH * WDIM * HID)  // 262144 tagged u32

typedef short short8 __attribute__((ext_vector_type(8)));
typedef float f32x4  __attribute__((ext_vector_type(4)));
typedef unsigned int u32x4 __attribute__((ext_vector_type(4)));

#define ALOAD(p)     __hip_atomic_load((p), __ATOMIC_RELAXED, __HIP_MEMORY_SCOPE_AGENT)
#define ASTORE(p, v) __hip_atomic_store((p), (v), __ATOMIC_RELAXED, __HIP_MEMORY_SCOPE_AGENT)

__device__ __forceinline__ unsigned short f2bf(float f) {
    union { float f; unsigned int u; } v; v.f = f;
    unsigned int r = v.u + 0x7fffu + ((v.u >> 16) & 1u);   // RNE
    return (unsigned short)(r >> 16);
}
__device__ __forceinline__ float sigm(float x)  { return 1.0f / (1.0f + __expf(-x)); }
__device__ __forceinline__ float tanhft(float x){ return 2.0f / (1.0f + __expf(-2.0f * x)) - 1.0f; }

// ---------------------------------------------------------------------------
// Pack: Wx / Wh in fragment order; Wh additionally CH-GROUPED: ks = grp*3 + t,
// c = grp*32 + (lane>>4)*8 + j  (grp = 32-ch group 0..3, t = tap 0..2).
// Also bias fold and tag-buffer zero (replay/graph-capture safe).
// ---------------------------------------------------------------------------
__global__ void pack_kernel(const float* __restrict__ W_is,
                            const float* __restrict__ b_is,
                            const float* __restrict__ W_ss,
                            const float* __restrict__ b_ss,
                            unsigned short* __restrict__ Wx,
                            unsigned short* __restrict__ Wh,
                            float* __restrict__ bias_p,
                            unsigned int* __restrict__ ht) {
    int idx = blockIdx.x * blockDim.x + threadIdx.x;
    if (idx < 131072) {                 // 8 he * WXSZ
        int j = idx & 7, lane = (idx >> 3) & 63, rest = idx >> 9;
        int ks = rest & 7, gg = rest >> 3, gate = gg & 3, he = gg >> 2;
        int n = gate * 128 + he * 16 + (lane & 15);
        int k = ks * 32 + ((lane >> 4) * 8) + j;        // k = t*128 + c
        Wx[idx] = f2bf(W_is[((size_t)n * CIN + (k & 127)) * 3 + (k >> 7)]);
    }
    if (idx < 196608) {                 // 8 he * WHSZ
        int j = idx & 7, lane = (idx >> 3) & 63, rest = idx >> 9;   // rest < 384
        int ks = rest % 12, gg = rest / 12, gate = gg & 3, he = gg >> 2;
        int grp = ks / 3, t = ks - 3 * grp;
        int c = grp * 32 + ((lane >> 4) * 8) + j;
        int n = gate * 128 + he * 16 + (lane & 15);
        Wh[idx] = f2bf(W_ss[((size_t)n * HID + c) * 3 + t]);
    }
    if (idx < 512) bias_p[idx] = b_is[idx] + b_ss[idx];
    if (idx < HTWORDS) ht[idx] = 0u;
}

// ---------------------------------------------------------------------------
// xt: x [b][c][r][w] f32 -> xT [b][r][w][c] bf16 (coalesced both sides via LDS)
// ---------------------------------------------------------------------------
__global__ __launch_bounds__(256) void xt_kernel(const float* __restrict__ x,
                                                 unsigned int* __restrict__ xT32) {
    __shared__ unsigned short t[128 * 66];
    const int tid = threadIdx.x;
    const int b = blockIdx.x >> 6;
    const int r = blockIdx.x & 63;
#pragma unroll
    for (int i = 0; i < 32; ++i) {
        int flat = i * 256 + tid;
        int c = flat >> 6, w = flat & 63;
        t[c * 66 + w] = f2bf(x[(((size_t)b * 128 + c) * 64 + r) * 64 + w]);
    }
    __syncthreads();
    unsigned* o = xT32 + ((size_t)(b * 64 + r) * 64) * 64;
#pragma unroll
    for (int i = 0; i < 16; ++i) {
        int flat = i * 256 + tid;
        int w = flat >> 6, cp = flat & 63;
        o[w * 64 + cp] = (unsigned)t[(2 * cp) * 66 + w]
                       | ((unsigned)t[(2 * cp + 1) * 66 + w] << 16);
    }
}

// ---------------------------------------------------------------------------
// Persistent LSTM: grid 128 = (b, he), 256 thr, 1 blk/CU. FULLY wave-
// autonomous: private per-wave LDS tiles, NO __syncthreads in the loop.
// Per row per wave: stage x(r+1) [pre-poll overlap] -> GEMM_X(r) -> for each
// 32-ch group g: {9-word tagged poll -> private LDS stage -> 3ks GEMM} ->
// epilogue -> tagged publish. Tagged word = (bf16<<16)|(row+1): data is its
// own flag (1 round-trip handshake). Parity ping-pong on ht; adjacency
// argument bounds skew (producer 2 rows ahead of a reader it feeds would
// require that reader already published -> contradiction) => race/deadlock
// free. setprio 0 in spin, 1 in work region.
// ---------------------------------------------------------------------------
__global__ __launch_bounds__(256, 1) void lstm_kernel(
        const unsigned int* __restrict__ xT32,
        const unsigned short* __restrict__ Wx,
        const unsigned short* __restrict__ Wh,
        const float* __restrict__ bias_p,
        unsigned int* ht,
        float* __restrict__ out) {
    __shared__ __align__(16) unsigned short lds_bx[WXSZ];           // 32 KiB
    __shared__ __align__(16) unsigned short lds_bh[WHSZ];           // 48 KiB
    __shared__ __align__(16) unsigned short ldsx[4][2][17 * LROW];  // 36.1 KiB
    __shared__ __align__(16) unsigned short ldsh[4][2][18 * LROW];  // 38.25 KiB

    const int tid  = threadIdx.x;
    const int b    = blockIdx.x & 15;      // partners share bid%8 -> same XCD (perf only)
    const int he   = blockIdx.x >> 4;
    const int wv   = tid >> 6;
    const int lane = tid & 63;
    const int quad = lane >> 4;
    const int l15  = lane & 15;

    // ---- prologue: weight slices -> LDS (block-coop, once) ----
    {
        const u32x4* src = (const u32x4*)(Wx + (size_t)he * WXSZ);
        u32x4* dst = (u32x4*)lds_bx;
#pragma unroll
        for (int p = 0; p < 8; ++p) dst[p * 256 + tid] = src[p * 256 + tid];
        const u32x4* srh = (const u32x4*)(Wh + (size_t)he * WHSZ);
        u32x4* dsh = (u32x4*)lds_bh;
#pragma unroll
        for (int p = 0; p < 12; ++p) dsh[p * 256 + tid] = srh[p * 256 + tid];
    }

#define STAGE_XW(ROW, XP)                                                      \
    {                                                                          \
        const unsigned* xs = xT32 + ((size_t)(b * 64 + (ROW)) * 64) * 64;      \
        _Pragma("unroll")                                                      \
        for (int i = 0; i < 17; ++i) {                                         \
            int rr = wv * 16 - 1 + i;                                          \
            unsigned v = (rr >= 0) ? xs[rr * 64 + lane] : 0u;                  \
            ((unsigned*)(XP))[i * 68 + lane] = v;                              \
        }                                                                      \
    }

#define GEMM_XW(XP)                                                            \
    {                                                                          \
        _Pragma("unroll")                                                      \
        for (int ks = 0; ks < 8; ++ks) {                                       \
            const int t = ks >> 2, c0 = (ks & 3) * 32;                         \
            short8 a = *(const short8*)&(XP)[(l15 + t) * LROW + c0 + quad * 8];\
            _Pragma("unroll")                                                  \
            for (int g = 0; g < 4; ++g) {                                      \
                short8 bq = *(const short8*)&lds_bx[((g * 8 + ks) * 64 + lane) * 8]; \
                acc[g] = __builtin_amdgcn_mfma_f32_16x16x32_bf16(a, bq, acc[g], 0, 0, 0); \
            }                                                                  \
        }                                                                      \
    }

// one 32-ch group: tagged poll (9 words/lane) -> private LDS stage -> 3ks GEMM
#define HGRP(GRP, WANT, HS, HP)                                                \
    {                                                                          \
        unsigned hv_[9];                                                       \
        __builtin_amdgcn_s_setprio(0);                                         \
        for (;;) {                                                             \
            unsigned diff = 0;                                                 \
            _Pragma("unroll")                                                  \
            for (int i = 0; i < 9; ++i) {                                      \
                int wi = i * 64 + lane;                                        \
                int row_i = wi >> 5, ch32 = wi & 31;                           \
                int rr = wv * 16 - 1 + row_i;                                  \
                unsigned v = ((unsigned)rr < 64u)                              \
                    ? ALOAD(&(HS)[rr * 128 + (GRP) * 32 + ch32])               \
                    : (unsigned)(WANT);                                        \
                hv_[i] = v;                                                    \
                diff |= (v ^ (unsigned)(WANT)) & 0xffffu;                      \
            }                                                                  \
            if (__ballot(diff != 0u) == 0ull) break;                          \
        }                                                                      \
        __builtin_amdgcn_s_setprio(1);                                         \
        _Pragma("unroll")                                                      \
        for (int i = 0; i < 9; ++i) {                                          \
            int wi = i * 64 + lane;                                            \
            int row_i = wi >> 5, ch32 = wi & 31;                               \
            (HP)[row_i * LROW + (GRP) * 32 + ch32] = (unsigned short)(hv_[i] >> 16); \
        }                                                                      \
        _Pragma("unroll")                                                      \
        for (int t = 0; t < 3; ++t) {                                          \
            const int ks = (GRP) * 3 + t;                                      \
            short8 a = *(const short8*)&(HP)[(l15 + t) * LROW + (GRP) * 32 + quad * 8]; \
            _Pragma("unroll")                                                  \
            for (int g = 0; g < 4; ++g) {                                      \
                short8 bq = *(const short8*)&lds_bh[((g * 12 + ks) * 64 + lane) * 8]; \
                acc[g] = __builtin_amdgcn_mfma_f32_16x16x32_bf16(a, bq, acc[g], 0, 0, 0); \
            }                                                                  \
        }                                                                      \
    }

    STAGE_XW(0, ldsx[wv][0]);            // per-wave x row 0
    __syncthreads();                     // weights ready (only barrier)
    __builtin_amdgcn_s_setprio(1);

    const int hch = he * 16 + l15;
    const float bi  = bias_p[      hch];
    const float bf_ = bias_p[128 + hch];
    const float bo  = bias_p[256 + hch];
    const float bg  = bias_p[384 + hch];

    f32x4 creg = (f32x4){0.f, 0.f, 0.f, 0.f};

    for (int r = 0; r < HDIM; ++r) {
        f32x4 acc[4];
#pragma unroll
        for (int g = 0; g < 4; ++g) acc[g] = (f32x4){0.f, 0.f, 0.f, 0.f};

        if (r < HDIM - 1) STAGE_XW(r + 1, ldsx[wv][(r + 1) & 1]);  // overlap
        GEMM_XW(ldsx[wv][r & 1]);                                   // x-part

        if (r > 0) {
            const unsigned* hs = ht + ((size_t)((r - 1) & 1) * NBATCH + b) * (WDIM * HID);
            unsigned short* hp = ldsh[wv][(r - 1) & 1];
            HGRP(0, r, hs, hp);
            HGRP(1, r, hs, hp);
            HGRP(2, r, hs, hp);
            HGRP(3, r, hs, hp);
        }

        // ---- epilogue: gates lane-local; publish tagged h FIRST ----
        {
            const int w0 = wv * 16 + quad * 4;
            f32x4 hv;
#pragma unroll
            for (int e = 0; e < 4; ++e) {
                float zi = acc[0][e] + bi;
                float zf = acc[1][e] + bf_;
                float zo = acc[2][e] + bo;
                float zg = acc[3][e] + bg;
                float ig = sigm(zi), fg = sigm(zf), og = sigm(zo);
                float gg = tanhft(zg);
                float cn = fg * creg[e] + ig * gg;
                creg[e] = cn;
                hv[e]   = og * tanhft(cn);
            }
            unsigned* hb = ht + ((size_t)(r & 1) * NBATCH + b) * (WDIM * HID);
#pragma unroll
            for (int e = 0; e < 4; ++e)
                ASTORE(&hb[(w0 + e) * 128 + hch],
                       ((unsigned)f2bf(hv[e]) << 16) | (unsigned)(r + 1));
            *(f32x4*)&out[(((size_t)b * HID + hch) * HDIM + r) * WDIM + w0] = hv;
        }
    }
}

extern "C" void kernel_launch(void* const* d_in, const int* in_sizes, int n_in,
                              void* d_out, int out_size, void* d_ws, size_t ws_size,
                              hipStream_t stream) {
    const float* x    = (const float*)d_in[0];
    const float* W_is = (const float*)d_in[1];
    const float* b_is = (const float*)d_in[2];
    const float* W_ss = (const float*)d_in[3];
    const float* b_ss = (const float*)d_in[4];
    float* out = (float*)d_out;

    // ws: xT bf16 [16][64][64][128] | ht u32[2][16][64][128] | Wx | Wh | bias
    const size_t XT_BYTES = (size_t)16 * 64 * 64 * 128 * 2;   // 16777216
    const size_t HT_BYTES = (size_t)HTWORDS * 4;              //  1048576
    const size_t WX_BYTES = 8 * WXSZ * 2;                     //   262144
    const size_t WH_BYTES = 8 * WHSZ * 2;                     //   393216

    unsigned int*   xT32   = (unsigned int*)d_ws;
    unsigned int*   ht     = (unsigned int*)((char*)d_ws + XT_BYTES);
    unsigned short* Wx     = (unsigned short*)((char*)d_ws + XT_BYTES + HT_BYTES);
    unsigned short* Wh     = (unsigned short*)((char*)d_ws + XT_BYTES + HT_BYTES + WX_BYTES);
    float*          bias_p = (float*)((char*)d_ws + XT_BYTES + HT_BYTES + WX_BYTES + WH_BYTES);

    pack_kernel<<<1024, 256, 0, stream>>>(W_is, b_is, W_ss, b_ss, Wx, Wh, bias_p, ht);
    xt_kernel<<<1024, 256, 0, stream>>>(x, xT32);
    lstm_kernel<<<128, 256, 0, stream>>>(xT32, Wx, Wh, bias_p, ht, out);
}